// Round 1
// baseline (858.921 us; speedup 1.0000x reference)
//
#include <hip/hip_runtime.h>
#include <hip/hip_bf16.h>

using bf16x8 = __attribute__((ext_vector_type(8))) short;
using f32x4  = __attribute__((ext_vector_type(4))) float;

#define MFMA_BF16(a, b, c) __builtin_amdgcn_mfma_f32_16x16x32_bf16((a), (b), (c), 0, 0, 0)

__device__ __forceinline__ unsigned short f2bf(float x) {
  union { float f; unsigned int u; } v; v.f = x;
  unsigned int r = v.u + 0x7fffu + ((v.u >> 16) & 1u);
  return (unsigned short)(r >> 16);
}

// ---------------- f32 -> bf16 convert ----------------
__global__ __launch_bounds__(256) void cvt_f32_bf16(const float* __restrict__ in,
                                                    unsigned short* __restrict__ out, int n) {
  int i = (blockIdx.x * 256 + threadIdx.x) * 4;
  if (i >= n) return;
  float4 f = *(const float4*)(in + i);
  ushort4 o;
  o.x = f2bf(f.x); o.y = f2bf(f.y); o.z = f2bf(f.z); o.w = f2bf(f.w);
  *(ushort4*)(out + i) = o;
}

// ---------------- BT-GEMM: C[m][n] = sum_k A[m][k] * Bw[n][k] ----------------
// M=8192, N=K=1024 baked. 128x128 tile, BK=32, 4 waves each 64x64.
// MODE 0: RoPE epilogue, bf16 out, layout [B,H,S,DK]
// MODE 1: bf16 out, transposed layout [B,H,DK,S]   (for V)
// MODE 2: f32 out, layout [M,N]                    (final projection)
template <int MODE>
__global__ __launch_bounds__(256) void gemm_bt(const unsigned short* __restrict__ A,
                                               const unsigned short* __restrict__ Bw,
                                               void* __restrict__ outp,
                                               const int* __restrict__ pos) {
  constexpr int K = 1024, N = 1024;
  __shared__ __align__(16) unsigned short As[128][40];  // +8 pad: 2-way bank conflicts only
  __shared__ __align__(16) unsigned short Bs[128][40];
  const int tid  = threadIdx.x;
  const int lane = tid & 63, wave = tid >> 6;
  const int wr = wave >> 1, wc = wave & 1;
  const int bm0 = blockIdx.y * 128, bn0 = blockIdx.x * 128;
  const int lrow = lane & 15, lko = (lane >> 4) * 8;
  const int srow = tid >> 2, scol = (tid & 3) * 8;
  const f32x4 z = {0.f, 0.f, 0.f, 0.f};
  f32x4 acc[4][4];
#pragma unroll
  for (int i = 0; i < 4; ++i)
#pragma unroll
    for (int j = 0; j < 4; ++j) acc[i][j] = z;

  for (int k0 = 0; k0 < K; k0 += 32) {
    bf16x8 a0 = *(const bf16x8*)(A + (size_t)(bm0 + srow) * K + k0 + scol);
    bf16x8 a1 = *(const bf16x8*)(A + (size_t)(bm0 + srow + 64) * K + k0 + scol);
    bf16x8 b0 = *(const bf16x8*)(Bw + (size_t)(bn0 + srow) * K + k0 + scol);
    bf16x8 b1 = *(const bf16x8*)(Bw + (size_t)(bn0 + srow + 64) * K + k0 + scol);
    __syncthreads();
    *(bf16x8*)&As[srow][scol] = a0;
    *(bf16x8*)&As[srow + 64][scol] = a1;
    *(bf16x8*)&Bs[srow][scol] = b0;
    *(bf16x8*)&Bs[srow + 64][scol] = b1;
    __syncthreads();
    bf16x8 af[4], bfr[4];
#pragma unroll
    for (int mi = 0; mi < 4; ++mi)
      af[mi] = *(const bf16x8*)&As[wr * 64 + mi * 16 + lrow][lko];
#pragma unroll
    for (int ni = 0; ni < 4; ++ni)
      bfr[ni] = *(const bf16x8*)&Bs[wc * 64 + ni * 16 + lrow][lko];
#pragma unroll
    for (int mi = 0; mi < 4; ++mi)
#pragma unroll
      for (int ni = 0; ni < 4; ++ni)
        acc[mi][ni] = MFMA_BF16(af[mi], bfr[ni], acc[mi][ni]);
  }

#pragma unroll
  for (int mi = 0; mi < 4; ++mi) {
#pragma unroll
    for (int r = 0; r < 4; ++r) {
      const int row = bm0 + wr * 64 + mi * 16 + (lane >> 4) * 4 + r;
#pragma unroll
      for (int ni = 0; ni < 4; ++ni) {
        const int col = bn0 + wc * 64 + ni * 16 + lrow;
        float v = acc[mi][ni][r];
        if (MODE == 2) {
          ((float*)outp)[(size_t)row * N + col] = v;
        } else {
          const int b = row >> 11, s = row & 2047;
          const int h = col >> 6, d = col & 63;
          if (MODE == 0) {
            // RoPE: pair partner (col^1) lives in lane^1; angle = pos * theta^(-(2i)/64)
            const float p = (float)pos[row];
            const float invf = exp2f((float)(d & ~1) * (-13.287712379549609f / 64.0f));
            float sn, cs;
            sincosf(p * invf, &sn, &cs);
            const float other = __shfl_xor(v, 1);
            const float rv = (d & 1) ? (other * sn + v * cs) : (v * cs - other * sn);
            ((unsigned short*)outp)[((size_t)(b * 16 + h) * 2048 + s) * 64 + d] = f2bf(rv);
          } else {  // MODE 1: V transposed for PV B-operand contiguity
            ((unsigned short*)outp)[((size_t)(b * 16 + h) * 64 + d) * 2048 + s] = f2bf(v);
          }
        }
      }
    }
  }
}

// ---------------- causal flash attention ----------------
// Q,K: [BH, S, DK] bf16 (RoPE applied); Vt: [BH, DK, S] bf16; O: [B,S,D] bf16.
// 4 waves/block, each owns 16 q-rows; KV tiles of 64; online softmax.
__global__ __launch_bounds__(256) void attn_fwd(const unsigned short* __restrict__ Q,
                                                const unsigned short* __restrict__ Kk,
                                                const unsigned short* __restrict__ Vt,
                                                unsigned short* __restrict__ O) {
  __shared__ __align__(16) unsigned short Plds[4][16][72];  // per-wave P tile, +8 pad
  const int bh = blockIdx.x >> 5, qb = blockIdx.x & 31;
  const int lane = threadIdx.x & 63, wave = threadIdx.x >> 6;
  const int q0 = qb * 64;
  const int lrow = lane & 15, lko = (lane >> 4) * 8;
  const unsigned short* Qb = Q + (size_t)bh * 2048 * 64;
  const unsigned short* Kb = Kk + (size_t)bh * 2048 * 64;
  const unsigned short* Vb = Vt + (size_t)bh * 64 * 2048;
  const int qrow = q0 + wave * 16;
  const bf16x8 qf0 = *(const bf16x8*)(Qb + (size_t)(qrow + lrow) * 64 + lko);
  const bf16x8 qf1 = *(const bf16x8*)(Qb + (size_t)(qrow + lrow) * 64 + 32 + lko);
  const f32x4 z = {0.f, 0.f, 0.f, 0.f};
  f32x4 acc[4] = {z, z, z, z};
  float mmax[4] = {-1e30f, -1e30f, -1e30f, -1e30f};
  float lsum[4] = {0.f, 0.f, 0.f, 0.f};

  for (int t = 0; t <= qb; ++t) {
    const int kv0 = t * 64;
    f32x4 sc[4];
#pragma unroll
    for (int n = 0; n < 4; ++n) {
      const bf16x8 kf0 = *(const bf16x8*)(Kb + (size_t)(kv0 + n * 16 + lrow) * 64 + lko);
      const bf16x8 kf1 = *(const bf16x8*)(Kb + (size_t)(kv0 + n * 16 + lrow) * 64 + 32 + lko);
      sc[n] = MFMA_BF16(qf0, kf0, z);
      sc[n] = MFMA_BF16(qf1, kf1, sc[n]);
    }
    const bool diag = (t == qb);
#pragma unroll
    for (int r = 0; r < 4; ++r) {
      const int rg = qrow + (lane >> 4) * 4 + r;
      float v0 = sc[0][r] * 0.125f;
      float v1 = sc[1][r] * 0.125f;
      float v2 = sc[2][r] * 0.125f;
      float v3 = sc[3][r] * 0.125f;
      if (diag) {
        if (kv0 + 0  + lrow > rg) v0 = -1e30f;
        if (kv0 + 16 + lrow > rg) v1 = -1e30f;
        if (kv0 + 32 + lrow > rg) v2 = -1e30f;
        if (kv0 + 48 + lrow > rg) v3 = -1e30f;
      }
      float mx = fmaxf(fmaxf(v0, v1), fmaxf(v2, v3));
#pragma unroll
      for (int off = 1; off < 16; off <<= 1) mx = fmaxf(mx, __shfl_xor(mx, off));
      const float newm = fmaxf(mmax[r], mx);
      const float scl = __expf(mmax[r] - newm);
      const float p0 = __expf(v0 - newm);
      const float p1 = __expf(v1 - newm);
      const float p2 = __expf(v2 - newm);
      const float p3 = __expf(v3 - newm);
      float rs = p0 + p1 + p2 + p3;
#pragma unroll
      for (int off = 1; off < 16; off <<= 1) rs += __shfl_xor(rs, off);
      lsum[r] = lsum[r] * scl + rs;
      mmax[r] = newm;
      acc[0][r] *= scl; acc[1][r] *= scl; acc[2][r] *= scl; acc[3][r] *= scl;
      const int prw = (lane >> 4) * 4 + r;
      Plds[wave][prw][0  + lrow] = f2bf(p0);
      Plds[wave][prw][16 + lrow] = f2bf(p1);
      Plds[wave][prw][32 + lrow] = f2bf(p2);
      Plds[wave][prw][48 + lrow] = f2bf(p3);
    }
    // within-wave LDS RAW: compiler inserts lgkmcnt waits; no barrier needed
    const bf16x8 pf0 = *(const bf16x8*)&Plds[wave][lrow][lko];
    const bf16x8 pf1 = *(const bf16x8*)&Plds[wave][lrow][32 + lko];
#pragma unroll
    for (int mt = 0; mt < 4; ++mt) {
      const bf16x8 vf0 = *(const bf16x8*)(Vb + (size_t)(mt * 16 + lrow) * 2048 + kv0 + lko);
      const bf16x8 vf1 = *(const bf16x8*)(Vb + (size_t)(mt * 16 + lrow) * 2048 + kv0 + 32 + lko);
      acc[mt] = MFMA_BF16(pf0, vf0, acc[mt]);
      acc[mt] = MFMA_BF16(pf1, vf1, acc[mt]);
    }
  }

  const int b = bh >> 4, h = bh & 15;
#pragma unroll
  for (int r = 0; r < 4; ++r) {
    const float inv = 1.0f / lsum[r];
    const int rg = qrow + (lane >> 4) * 4 + r;
#pragma unroll
    for (int mt = 0; mt < 4; ++mt) {
      O[((size_t)b * 2048 + rg) * 1024 + h * 64 + mt * 16 + lrow] = f2bf(acc[mt][r] * inv);
    }
  }
}

extern "C" void kernel_launch(void* const* d_in, const int* in_sizes, int n_in,
                              void* d_out, int out_size, void* d_ws, size_t ws_size,
                              hipStream_t stream) {
  const float* x  = (const float*)d_in[0];
  const float* qw = (const float*)d_in[1];
  const float* kw = (const float*)d_in[2];
  const float* vw = (const float*)d_in[3];
  const float* ow = (const float*)d_in[4];
  const int* pos  = (const int*)d_in[5];
  float* out = (float*)d_out;

  // workspace layout (bf16 elements)
  unsigned short* xb  = (unsigned short*)d_ws;            // [8192,1024]
  unsigned short* qwb = xb  + (size_t)8192 * 1024;        // [1024,1024]
  unsigned short* kwb = qwb + (size_t)1024 * 1024;
  unsigned short* vwb = kwb + (size_t)1024 * 1024;
  unsigned short* owb = vwb + (size_t)1024 * 1024;
  unsigned short* Qr  = owb + (size_t)1024 * 1024;        // [BH,S,DK]
  unsigned short* Kr  = Qr  + (size_t)8192 * 1024;        // [BH,S,DK]
  unsigned short* Vtr = Kr  + (size_t)8192 * 1024;        // [BH,DK,S]
  unsigned short* AO  = Vtr + (size_t)8192 * 1024;        // [8192,1024]

  cvt_f32_bf16<<<8192, 256, 0, stream>>>(x,  xb,  8192 * 1024);
  cvt_f32_bf16<<<1024, 256, 0, stream>>>(qw, qwb, 1024 * 1024);
  cvt_f32_bf16<<<1024, 256, 0, stream>>>(kw, kwb, 1024 * 1024);
  cvt_f32_bf16<<<1024, 256, 0, stream>>>(vw, vwb, 1024 * 1024);
  cvt_f32_bf16<<<1024, 256, 0, stream>>>(ow, owb, 1024 * 1024);

  dim3 gg(8, 64);  // (N/128, M/128)
  gemm_bt<0><<<gg, 256, 0, stream>>>(xb, qwb, Qr,  pos);
  gemm_bt<0><<<gg, 256, 0, stream>>>(xb, kwb, Kr,  pos);
  gemm_bt<1><<<gg, 256, 0, stream>>>(xb, vwb, Vtr, pos);
  attn_fwd<<<2048, 256, 0, stream>>>(Qr, Kr, Vtr, AO);
  gemm_bt<2><<<gg, 256, 0, stream>>>(AO, owb, out, nullptr);
}

// Round 2
// 742.704 us; speedup vs baseline: 1.1565x; 1.1565x over previous
//
#include <hip/hip_runtime.h>
#include <hip/hip_bf16.h>

using bf16x8 = __attribute__((ext_vector_type(8))) short;
using f32x4  = __attribute__((ext_vector_type(4))) float;

#define MFMA_BF16(a, b, c) __builtin_amdgcn_mfma_f32_16x16x32_bf16((a), (b), (c), 0, 0, 0)

__device__ __forceinline__ unsigned short f2bf(float x) {
  union { float f; unsigned int u; } v; v.f = x;
  unsigned int r = v.u + 0x7fffu + ((v.u >> 16) & 1u);
  return (unsigned short)(r >> 16);
}

__device__ __forceinline__ void gload16(const void* g, void* l) {
  __builtin_amdgcn_global_load_lds(
      (const __attribute__((address_space(1))) unsigned int*)g,
      (__attribute__((address_space(3))) unsigned int*)l, 16, 0, 0);
}

// ---------------- f32 -> bf16 convert ----------------
__global__ __launch_bounds__(256) void cvt_f32_bf16(const float* __restrict__ in,
                                                    unsigned short* __restrict__ out, int n) {
  int i = (blockIdx.x * 256 + threadIdx.x) * 4;
  if (i >= n) return;
  float4 f = *(const float4*)(in + i);
  ushort4 o;
  o.x = f2bf(f.x); o.y = f2bf(f.y); o.z = f2bf(f.z); o.w = f2bf(f.w);
  *(ushort4*)(out + i) = o;
}

// ---------------- BT-GEMM: C[m][n] = sum_k A[m][k] * Bw[n][k] ----------------
// M=8192, N=K=1024 baked. 128x128 tile, BK=32, 4 waves each 64x64.
// Staging via global_load_lds width=16 (m97 pattern), linear LDS [128][32].
// MODE 0: RoPE epilogue, bf16 out, layout [B,H,S,DK]
// MODE 1: bf16 out, transposed layout [B,H,DK,S]   (for V)
// MODE 2: f32 out, layout [M,N]                    (final projection)
template <int MODE>
__global__ __launch_bounds__(256) void gemm_bt(const unsigned short* __restrict__ A,
                                               const unsigned short* __restrict__ Bw,
                                               void* __restrict__ outp,
                                               const int* __restrict__ pos) {
  constexpr int K = 1024, N = 1024;
  __shared__ __align__(16) unsigned short As[128][32];  // linear: global_load_lds dest
  __shared__ __align__(16) unsigned short Bs[128][32];
  const int tid  = threadIdx.x;
  const int lane = tid & 63, wave = tid >> 6;
  const int wr = wave >> 1, wc = wave & 1;
  const int bm0 = blockIdx.y * 128, bn0 = blockIdx.x * 128;
  const int lrow = lane & 15, lko = (lane >> 4) * 8;
  // staging: chunk c = wave*64+lane (+256 for pass 1); row=c>>2, col=(lane&3)*8
  const int srow = wave * 16 + (lane >> 2);
  const int scol = (lane & 3) * 8;
  const unsigned short* gA = A + (size_t)(bm0 + srow) * K + scol;
  const unsigned short* gB = Bw + (size_t)(bn0 + srow) * K + scol;
  char* lA = (char*)(&As[0][0]) + wave * 1024;  // wave-uniform base; lane adds lane*16
  char* lB = (char*)(&Bs[0][0]) + wave * 1024;
  const f32x4 z = {0.f, 0.f, 0.f, 0.f};
  f32x4 acc[4][4];
#pragma unroll
  for (int i = 0; i < 4; ++i)
#pragma unroll
    for (int j = 0; j < 4; ++j) acc[i][j] = z;

  for (int k0 = 0; k0 < K; k0 += 32) {
    __syncthreads();  // prev iter's LDS reads done before overwrite
    gload16(gA + k0, lA);
    gload16(gA + k0 + (size_t)64 * K, lA + 4096);
    gload16(gB + k0, lB);
    gload16(gB + k0 + (size_t)64 * K, lB + 4096);
    __syncthreads();  // drains vmcnt -> staged data visible
    bf16x8 af[4], bfr[4];
#pragma unroll
    for (int mi = 0; mi < 4; ++mi)
      af[mi] = *(const bf16x8*)&As[wr * 64 + mi * 16 + lrow][lko];
#pragma unroll
    for (int ni = 0; ni < 4; ++ni)
      bfr[ni] = *(const bf16x8*)&Bs[wc * 64 + ni * 16 + lrow][lko];
#pragma unroll
    for (int mi = 0; mi < 4; ++mi)
#pragma unroll
      for (int ni = 0; ni < 4; ++ni)
        acc[mi][ni] = MFMA_BF16(af[mi], bfr[ni], acc[mi][ni]);
  }

#pragma unroll
  for (int mi = 0; mi < 4; ++mi) {
#pragma unroll
    for (int r = 0; r < 4; ++r) {
      const int row = bm0 + wr * 64 + mi * 16 + (lane >> 4) * 4 + r;
#pragma unroll
      for (int ni = 0; ni < 4; ++ni) {
        const int col = bn0 + wc * 64 + ni * 16 + lrow;
        float v = acc[mi][ni][r];
        if (MODE == 2) {
          ((float*)outp)[(size_t)row * N + col] = v;
        } else {
          const int b = row >> 11, s = row & 2047;
          const int h = col >> 6, d = col & 63;
          if (MODE == 0) {
            // RoPE: pair partner (col^1) lives in lane^1
            const float p = (float)pos[row];
            const float invf = exp2f((float)(d & ~1) * (-13.287712379549609f / 64.0f));
            float sn, cs;
            sincosf(p * invf, &sn, &cs);
            const float other = __shfl_xor(v, 1);
            const float rv = (d & 1) ? (other * sn + v * cs) : (v * cs - other * sn);
            ((unsigned short*)outp)[((size_t)(b * 16 + h) * 2048 + s) * 64 + d] = f2bf(rv);
          } else {  // MODE 1: V transposed for PV A-operand contiguity
            ((unsigned short*)outp)[((size_t)(b * 16 + h) * 64 + d) * 2048 + s] = f2bf(v);
          }
        }
      }
    }
  }
}

// ---------------- causal flash attention (swapped QK^T) ----------------
// Q,K: [BH,S,DK] bf16 (RoPE applied); Vt: [BH,DK,S] bf16; O: [B,S,D] bf16.
// 4 waves/block, each owns 16 q-rows. S^T = mfma(K,Q): lane holds
// (kk = kv0+n*16+hi*4+r, q = qrow+lrow). Softmax state lane-local.
// O^T = mfma(Vt,P): acc[dt][r] = O[q][dt*16+hi*4+r].
__global__ __launch_bounds__(256) void attn_fwd(const unsigned short* __restrict__ Q,
                                                const unsigned short* __restrict__ Kk,
                                                const unsigned short* __restrict__ Vt,
                                                unsigned short* __restrict__ O) {
  __shared__ __align__(16) unsigned short Plds[4][16][72];  // per-wave P tile
  // XCD swizzle: 2048 blocks = 8 XCD x 256; 8 heads/XCD; long blocks (high qb) first
  const int p = blockIdx.x;
  const int L = (p & 7) * 256 + (p >> 3);
  const int bh = L >> 5;
  const int qb = 31 - (L & 31);
  const int lane = threadIdx.x & 63, wave = threadIdx.x >> 6;
  const int lrow = lane & 15, hi = lane >> 4, lko = hi * 8;
  const unsigned short* Qb = Q + (size_t)bh * 2048 * 64;
  const unsigned short* Kb = Kk + (size_t)bh * 2048 * 64;
  const unsigned short* Vb = Vt + (size_t)bh * 64 * 2048;
  const int qrow = qb * 64 + wave * 16;
  const int qg = qrow + lrow;  // this lane's q row
  const bf16x8 qf0 = *(const bf16x8*)(Qb + (size_t)qg * 64 + lko);
  const bf16x8 qf1 = *(const bf16x8*)(Qb + (size_t)qg * 64 + 32 + lko);
  const f32x4 z = {0.f, 0.f, 0.f, 0.f};
  f32x4 acc[4] = {z, z, z, z};
  float m = -1e30f, l = 0.f;

  for (int t = 0; t <= qb; ++t) {
    const int kv0 = t * 64;
    f32x4 st[4];
#pragma unroll
    for (int n = 0; n < 4; ++n) {
      const bf16x8 kf0 = *(const bf16x8*)(Kb + (size_t)(kv0 + n * 16 + lrow) * 64 + lko);
      const bf16x8 kf1 = *(const bf16x8*)(Kb + (size_t)(kv0 + n * 16 + lrow) * 64 + 32 + lko);
      st[n] = MFMA_BF16(kf0, qf0, z);
      st[n] = MFMA_BF16(kf1, qf1, st[n]);
    }
    float pv[16];
    float pmax = -1e30f;
    const bool diag = (t == qb);
#pragma unroll
    for (int n = 0; n < 4; ++n)
#pragma unroll
      for (int r = 0; r < 4; ++r) {
        float v = st[n][r] * 0.125f;
        if (diag && (kv0 + n * 16 + hi * 4 + r > qg)) v = -1e30f;
        pv[n * 4 + r] = v;
        pmax = fmaxf(pmax, v);
      }
    pmax = fmaxf(pmax, __shfl_xor(pmax, 16));
    pmax = fmaxf(pmax, __shfl_xor(pmax, 32));
    const float newm = fmaxf(m, pmax);
    const float scl = __expf(m - newm);
    float rs = 0.f;
#pragma unroll
    for (int i = 0; i < 16; ++i) {
      pv[i] = __expf(pv[i] - newm);
      rs += pv[i];
    }
    rs += __shfl_xor(rs, 16);
    rs += __shfl_xor(rs, 32);
    l = l * scl + rs;
    m = newm;
#pragma unroll
    for (int dt = 0; dt < 4; ++dt) acc[dt] *= scl;
    // P -> LDS: row q=lrow, cols k = n*16+hi*4 .. +3 (r contiguous), 4x ds_write_b64
#pragma unroll
    for (int n = 0; n < 4; ++n) {
      ushort4 pk;
      pk.x = f2bf(pv[n * 4 + 0]); pk.y = f2bf(pv[n * 4 + 1]);
      pk.z = f2bf(pv[n * 4 + 2]); pk.w = f2bf(pv[n * 4 + 3]);
      *(ushort4*)&Plds[wave][lrow][n * 16 + hi * 4] = pk;
    }
    // within-wave LDS RAW: DS ops execute in order per wave; compiler inserts lgkmcnt
    const bf16x8 pf0 = *(const bf16x8*)&Plds[wave][lrow][lko];
    const bf16x8 pf1 = *(const bf16x8*)&Plds[wave][lrow][32 + lko];
#pragma unroll
    for (int dt = 0; dt < 4; ++dt) {
      const bf16x8 vf0 = *(const bf16x8*)(Vb + (size_t)(dt * 16 + lrow) * 2048 + kv0 + lko);
      const bf16x8 vf1 = *(const bf16x8*)(Vb + (size_t)(dt * 16 + lrow) * 2048 + kv0 + 32 + lko);
      acc[dt] = MFMA_BF16(vf0, pf0, acc[dt]);
      acc[dt] = MFMA_BF16(vf1, pf1, acc[dt]);
    }
  }

  const int b = bh >> 4, h = bh & 15;
  const float inv = 1.0f / l;
#pragma unroll
  for (int dt = 0; dt < 4; ++dt) {
    ushort4 ov;
    ov.x = f2bf(acc[dt][0] * inv); ov.y = f2bf(acc[dt][1] * inv);
    ov.z = f2bf(acc[dt][2] * inv); ov.w = f2bf(acc[dt][3] * inv);
    *(ushort4*)&O[((size_t)b * 2048 + qg) * 1024 + h * 64 + dt * 16 + hi * 4] = ov;
  }
}

extern "C" void kernel_launch(void* const* d_in, const int* in_sizes, int n_in,
                              void* d_out, int out_size, void* d_ws, size_t ws_size,
                              hipStream_t stream) {
  const float* x  = (const float*)d_in[0];
  const float* qw = (const float*)d_in[1];
  const float* kw = (const float*)d_in[2];
  const float* vw = (const float*)d_in[3];
  const float* ow = (const float*)d_in[4];
  const int* pos  = (const int*)d_in[5];
  float* out = (float*)d_out;

  // workspace layout (bf16 elements)
  unsigned short* xb  = (unsigned short*)d_ws;            // [8192,1024]
  unsigned short* qwb = xb  + (size_t)8192 * 1024;        // [1024,1024]
  unsigned short* kwb = qwb + (size_t)1024 * 1024;
  unsigned short* vwb = kwb + (size_t)1024 * 1024;
  unsigned short* owb = vwb + (size_t)1024 * 1024;
  unsigned short* Qr  = owb + (size_t)1024 * 1024;        // [BH,S,DK]
  unsigned short* Kr  = Qr  + (size_t)8192 * 1024;        // [BH,S,DK]
  unsigned short* Vtr = Kr  + (size_t)8192 * 1024;        // [BH,DK,S]
  unsigned short* AO  = Vtr + (size_t)8192 * 1024;        // [8192,1024]

  cvt_f32_bf16<<<8192, 256, 0, stream>>>(x,  xb,  8192 * 1024);
  cvt_f32_bf16<<<1024, 256, 0, stream>>>(qw, qwb, 1024 * 1024);
  cvt_f32_bf16<<<1024, 256, 0, stream>>>(kw, kwb, 1024 * 1024);
  cvt_f32_bf16<<<1024, 256, 0, stream>>>(vw, vwb, 1024 * 1024);
  cvt_f32_bf16<<<1024, 256, 0, stream>>>(ow, owb, 1024 * 1024);

  dim3 gg(8, 64);  // (N/128, M/128)
  gemm_bt<0><<<gg, 256, 0, stream>>>(xb, qwb, Qr,  pos);
  gemm_bt<0><<<gg, 256, 0, stream>>>(xb, kwb, Kr,  pos);
  gemm_bt<1><<<gg, 256, 0, stream>>>(xb, vwb, Vtr, pos);
  attn_fwd<<<2048, 256, 0, stream>>>(Qr, Kr, Vtr, AO);
  gemm_bt<2><<<gg, 256, 0, stream>>>(AO, owb, out, nullptr);
}

// Round 3
// 672.468 us; speedup vs baseline: 1.2773x; 1.1044x over previous
//
#include <hip/hip_runtime.h>
#include <hip/hip_bf16.h>

using bf16x8 = __attribute__((ext_vector_type(8))) short;
using f32x4  = __attribute__((ext_vector_type(4))) float;

#define MFMA_BF16(a, b, c) __builtin_amdgcn_mfma_f32_16x16x32_bf16((a), (b), (c), 0, 0, 0)

__device__ __forceinline__ unsigned short f2bf(float x) {
  union { float f; unsigned int u; } v; v.f = x;
  unsigned int r = v.u + 0x7fffu + ((v.u >> 16) & 1u);
  return (unsigned short)(r >> 16);
}

__device__ __forceinline__ void gload16(const void* g, void* l) {
  __builtin_amdgcn_global_load_lds(
      (const __attribute__((address_space(1))) unsigned int*)g,
      (__attribute__((address_space(3))) unsigned int*)l, 16, 0, 0);
}

// ---------------- f32 -> bf16 convert ----------------
__global__ __launch_bounds__(256) void cvt_f32_bf16(const float* __restrict__ in,
                                                    unsigned short* __restrict__ out, int n) {
  int i = (blockIdx.x * 256 + threadIdx.x) * 4;
  if (i >= n) return;
  float4 f = *(const float4*)(in + i);
  ushort4 o;
  o.x = f2bf(f.x); o.y = f2bf(f.y); o.z = f2bf(f.z); o.w = f2bf(f.w);
  *(ushort4*)(out + i) = o;
}

// ---------------- BT-GEMM: C[m][n] = sum_k A[m][k] * Bw[n][k] ----------------
// M=8192, K=1024 baked. 128x128 tile, BK=32, 4 waves each 64x64.
// MODE 3: fused QKV (Bw = [3072][1024] contiguous qw|kw|vw). RoPE on Q,K ->
//         [BH,S,DK]; V transposed -> [BH,DK,S]. outp = Qr (Kr,Vtr at +8M each).
// MODE 2: f32 out, [M,1024] (final projection)
template <int MODE>
__global__ __launch_bounds__(256) void gemm_bt(const unsigned short* __restrict__ A,
                                               const unsigned short* __restrict__ Bw,
                                               void* __restrict__ outp,
                                               const int* __restrict__ pos) {
  constexpr int K = 1024;
  __shared__ __align__(16) unsigned short As[128][32];  // linear: global_load_lds dest
  __shared__ __align__(16) unsigned short Bs[128][32];
  const int tid  = threadIdx.x;
  const int lane = tid & 63, wave = tid >> 6;
  const int wr = wave >> 1, wc = wave & 1;
  const int bm0 = blockIdx.y * 128, bn0 = blockIdx.x * 128;
  const int lrow = lane & 15, lko = (lane >> 4) * 8;
  const int srow = wave * 16 + (lane >> 2);
  const int scol = (lane & 3) * 8;
  const unsigned short* gA = A + (size_t)(bm0 + srow) * K + scol;
  const unsigned short* gB = Bw + (size_t)(bn0 + srow) * K + scol;
  char* lA = (char*)(&As[0][0]) + wave * 1024;  // wave-uniform base; lane adds lane*16
  char* lB = (char*)(&Bs[0][0]) + wave * 1024;
  const f32x4 z = {0.f, 0.f, 0.f, 0.f};
  f32x4 acc[4][4];
#pragma unroll
  for (int i = 0; i < 4; ++i)
#pragma unroll
    for (int j = 0; j < 4; ++j) acc[i][j] = z;

  for (int k0 = 0; k0 < K; k0 += 32) {
    __syncthreads();
    gload16(gA + k0, lA);
    gload16(gA + k0 + (size_t)64 * K, lA + 4096);
    gload16(gB + k0, lB);
    gload16(gB + k0 + (size_t)64 * K, lB + 4096);
    __syncthreads();
    bf16x8 af[4], bfr[4];
#pragma unroll
    for (int mi = 0; mi < 4; ++mi)
      af[mi] = *(const bf16x8*)&As[wr * 64 + mi * 16 + lrow][lko];
#pragma unroll
    for (int ni = 0; ni < 4; ++ni)
      bfr[ni] = *(const bf16x8*)&Bs[wc * 64 + ni * 16 + lrow][lko];
#pragma unroll
    for (int mi = 0; mi < 4; ++mi)
#pragma unroll
      for (int ni = 0; ni < 4; ++ni)
        acc[mi][ni] = MFMA_BF16(af[mi], bfr[ni], acc[mi][ni]);
  }

  unsigned short* Qr  = (unsigned short*)outp;
  unsigned short* Kr  = Qr + (size_t)8388608;
  unsigned short* Vtr = Qr + (size_t)16777216;
#pragma unroll
  for (int mi = 0; mi < 4; ++mi) {
#pragma unroll
    for (int r = 0; r < 4; ++r) {
      const int row = bm0 + wr * 64 + mi * 16 + (lane >> 4) * 4 + r;
#pragma unroll
      for (int ni = 0; ni < 4; ++ni) {
        const int col = bn0 + wc * 64 + ni * 16 + lrow;
        float v = acc[mi][ni][r];
        if (MODE == 2) {
          ((float*)outp)[(size_t)row * 1024 + col] = v;
        } else {  // MODE 3
          const int proj = col >> 10;   // wave-uniform
          const int c = col & 1023;
          const int h = c >> 6, d = c & 63;
          const int b = row >> 11, s = row & 2047;
          if (proj == 2) {
            Vtr[((size_t)(b * 16 + h) * 64 + d) * 2048 + s] = f2bf(v);
          } else {
            const float p = (float)pos[row];
            const float invf = exp2f((float)(d & ~1) * (-13.287712379549609f / 64.0f));
            float sn, cs;
            sincosf(p * invf, &sn, &cs);
            const float other = __shfl_xor(v, 1);
            const float rv = (d & 1) ? (other * sn + v * cs) : (v * cs - other * sn);
            unsigned short* dst = proj ? Kr : Qr;
            dst[((size_t)(b * 16 + h) * 2048 + s) * 64 + d] = f2bf(rv);
          }
        }
      }
    }
  }
}

// ---------------- causal flash attention (swapped QK^T, LDS-staged K/V) ----------------
// Q,K: [BH,S,DK] bf16 (RoPE applied); Vt: [BH,DK,S] bf16; O: [B,S,D] bf16.
// Grid 1024: 64 bh x 16 pairs; block processes qb=pair then qb=31-pair (33 tiles
// total -> perfectly balanced). K,V tiles staged to LDS via global_load_lds with
// XOR-swizzled global source (linear LDS dest), 2-way-conflict-free ds_read_b128.
__global__ __launch_bounds__(256) void attn_fwd(const unsigned short* __restrict__ Q,
                                                const unsigned short* __restrict__ Kk,
                                                const unsigned short* __restrict__ Vt,
                                                unsigned short* __restrict__ O) {
  __shared__ __align__(16) unsigned short Ks[4096];   // [64][64] swizzled
  __shared__ __align__(16) unsigned short Vs[4096];   // [64 d][64 kv] swizzled
  __shared__ __align__(16) unsigned short Plds[4][16][72];
  const int p = blockIdx.x;
  const int L = (p & 7) * 128 + (p >> 3);  // XCD swizzle: 8 heads/XCD
  const int bh = L >> 4, pair = L & 15;
  const int tid = threadIdx.x;
  const int lane = tid & 63, wave = tid >> 6;
  const int lrow = lane & 15, hi = lane >> 4;
  const unsigned short* Qb = Q + (size_t)bh * 2048 * 64;
  const unsigned short* Kb = Kk + (size_t)bh * 2048 * 64;
  const unsigned short* Vb = Vt + (size_t)bh * 64 * 2048;
  // staging map: chunk idx=tid (+256): row=idx>>3, cc=idx&7; fetch global col
  // block cc^(row&7) so that LDS-linear == swizzled layout
  const int rowA = tid >> 3;                           // 0..31
  const int colA = ((tid & 7) ^ (rowA & 7)) * 8;
  const int rowB = rowA + 32;
  const int colB = ((tid & 7) ^ (rowB & 7)) * 8;
  char* kBase0 = (char*)Ks + wave * 1024;
  char* kBase1 = (char*)Ks + 4096 + wave * 1024;
  char* vBase0 = (char*)Vs + wave * 1024;
  char* vBase1 = (char*)Vs + 4096 + wave * 1024;
  const int b = bh >> 4, h = bh & 15;
  const f32x4 z = {0.f, 0.f, 0.f, 0.f};
  constexpr float SCALE = 0.18033688011112042f;  // 0.125 * log2(e)

  for (int half = 0; half < 2; ++half) {
    const int qb = half ? (31 - pair) : pair;
    const int qrow = qb * 64 + wave * 16;
    const int qg = qrow + lrow;  // this lane's q row
    const bf16x8 qf0 = *(const bf16x8*)(Qb + (size_t)qg * 64 + hi * 8);
    const bf16x8 qf1 = *(const bf16x8*)(Qb + (size_t)qg * 64 + 32 + hi * 8);
    f32x4 acc[4] = {z, z, z, z};
    float m = -1e30f, l = 0.f;

    for (int t = 0; t <= qb; ++t) {
      const int kv0 = t * 64;
      __syncthreads();  // prev tile's LDS reads done
      gload16(Kb + (size_t)(kv0 + rowA) * 64 + colA, kBase0);
      gload16(Kb + (size_t)(kv0 + rowB) * 64 + colB, kBase1);
      gload16(Vb + (size_t)rowA * 2048 + kv0 + colA, vBase0);
      gload16(Vb + (size_t)rowB * 2048 + kv0 + colB, vBase1);
      __syncthreads();  // drains vmcnt -> staged tiles visible

      f32x4 st[4];
#pragma unroll
      for (int n = 0; n < 4; ++n) {
        const int rk = n * 16 + lrow;
        const int sw = lrow & 7;
        const bf16x8 kf0 = *(const bf16x8*)((char*)Ks + rk * 128 + ((hi ^ sw) * 16));
        const bf16x8 kf1 = *(const bf16x8*)((char*)Ks + rk * 128 + (((4 + hi) ^ sw) * 16));
        st[n] = MFMA_BF16(kf0, qf0, z);
        st[n] = MFMA_BF16(kf1, qf1, st[n]);
      }
      float pv[16];
      float pmax = -1e30f;
      const bool diag = (t == qb);
#pragma unroll
      for (int n = 0; n < 4; ++n)
#pragma unroll
        for (int r = 0; r < 4; ++r) {
          float v = st[n][r] * SCALE;
          if (diag && (kv0 + n * 16 + hi * 4 + r > qg)) v = -1e30f;
          pv[n * 4 + r] = v;
          pmax = fmaxf(pmax, v);
        }
      pmax = fmaxf(pmax, __shfl_xor(pmax, 16));
      pmax = fmaxf(pmax, __shfl_xor(pmax, 32));
      const float newm = fmaxf(m, pmax);
      const float scl = exp2f(m - newm);
      float rs = 0.f;
#pragma unroll
      for (int i = 0; i < 16; ++i) {
        pv[i] = exp2f(pv[i] - newm);
        rs += pv[i];
      }
      rs += __shfl_xor(rs, 16);
      rs += __shfl_xor(rs, 32);
      l = l * scl + rs;
      m = newm;
#pragma unroll
      for (int dt = 0; dt < 4; ++dt) acc[dt] *= scl;
#pragma unroll
      for (int n = 0; n < 4; ++n) {
        ushort4 pk;
        pk.x = f2bf(pv[n * 4 + 0]); pk.y = f2bf(pv[n * 4 + 1]);
        pk.z = f2bf(pv[n * 4 + 2]); pk.w = f2bf(pv[n * 4 + 3]);
        *(ushort4*)&Plds[wave][lrow][n * 16 + hi * 4] = pk;
      }
      // within-wave LDS RAW: DS ops in order per wave; compiler inserts lgkmcnt
      const bf16x8 pf0 = *(const bf16x8*)&Plds[wave][lrow][hi * 8];
      const bf16x8 pf1 = *(const bf16x8*)&Plds[wave][lrow][32 + hi * 8];
#pragma unroll
      for (int dt = 0; dt < 4; ++dt) {
        const int rv = dt * 16 + lrow;
        const int sw = lrow & 7;
        const bf16x8 vf0 = *(const bf16x8*)((char*)Vs + rv * 128 + ((hi ^ sw) * 16));
        const bf16x8 vf1 = *(const bf16x8*)((char*)Vs + rv * 128 + (((4 + hi) ^ sw) * 16));
        acc[dt] = MFMA_BF16(vf0, pf0, acc[dt]);
        acc[dt] = MFMA_BF16(vf1, pf1, acc[dt]);
      }
    }

    const float inv = 1.0f / l;
#pragma unroll
    for (int dt = 0; dt < 4; ++dt) {
      ushort4 ov;
      ov.x = f2bf(acc[dt][0] * inv); ov.y = f2bf(acc[dt][1] * inv);
      ov.z = f2bf(acc[dt][2] * inv); ov.w = f2bf(acc[dt][3] * inv);
      *(ushort4*)&O[((size_t)b * 2048 + qg) * 1024 + h * 64 + dt * 16 + hi * 4] = ov;
    }
  }
}

extern "C" void kernel_launch(void* const* d_in, const int* in_sizes, int n_in,
                              void* d_out, int out_size, void* d_ws, size_t ws_size,
                              hipStream_t stream) {
  const float* x  = (const float*)d_in[0];
  const float* qw = (const float*)d_in[1];
  const float* kw = (const float*)d_in[2];
  const float* vw = (const float*)d_in[3];
  const float* ow = (const float*)d_in[4];
  const int* pos  = (const int*)d_in[5];
  float* out = (float*)d_out;

  // workspace layout (bf16 elements)
  unsigned short* xb  = (unsigned short*)d_ws;            // [8192,1024]
  unsigned short* qwb = xb  + (size_t)8192 * 1024;        // [3072,1024] fused qkv
  unsigned short* kwb = qwb + (size_t)1024 * 1024;
  unsigned short* vwb = kwb + (size_t)1024 * 1024;
  unsigned short* owb = vwb + (size_t)1024 * 1024;
  unsigned short* Qr  = owb + (size_t)1024 * 1024;        // [BH,S,DK]
  unsigned short* Kr  = Qr  + (size_t)8192 * 1024;        // [BH,S,DK]
  unsigned short* Vtr = Kr  + (size_t)8192 * 1024;        // [BH,DK,S]
  unsigned short* AO  = Vtr + (size_t)8192 * 1024;        // [8192,1024]
  (void)Kr; (void)Vtr;

  cvt_f32_bf16<<<8192, 256, 0, stream>>>(x,  xb,  8192 * 1024);
  cvt_f32_bf16<<<1024, 256, 0, stream>>>(qw, qwb, 1024 * 1024);
  cvt_f32_bf16<<<1024, 256, 0, stream>>>(kw, kwb, 1024 * 1024);
  cvt_f32_bf16<<<1024, 256, 0, stream>>>(vw, vwb, 1024 * 1024);
  cvt_f32_bf16<<<1024, 256, 0, stream>>>(ow, owb, 1024 * 1024);

  dim3 gqkv(24, 64);  // (3072/128, 8192/128)
  gemm_bt<3><<<gqkv, 256, 0, stream>>>(xb, qwb, Qr, pos);
  attn_fwd<<<1024, 256, 0, stream>>>(Qr, Kr, Vtr, AO);
  dim3 go(8, 64);
  gemm_bt<2><<<go, 256, 0, stream>>>(AO, owb, out, nullptr);
}